// Round 1
// baseline (5493.778 us; speedup 1.0000x reference)
//
#include <hip/hip_runtime.h>

#define NSRC1 500000
#define NDST1 100000
#define NDST2 20000
#define NE1   2000000
#define NE2   1000000
#define F     128
#define NCLS  16

// ---------------------------------------------------------------------------
// Edge aggregation: s[dst] += table[src]*w ; deg[dst] += 1
// 32 lanes per edge, each lane handles 4 consecutive floats (float4).
// ---------------------------------------------------------------------------
__global__ __launch_bounds__(256) void edge_kernel(
    const float4* __restrict__ table, const int* __restrict__ src,
    const int* __restrict__ dst, const float* __restrict__ w,
    float* __restrict__ s, float* __restrict__ deg, int nEdges)
{
    int t = blockIdx.x * 256 + threadIdx.x;
    int e = t >> 5;
    if (e >= nEdges) return;
    int l = t & 31;
    int sr = src[e];
    int dd = dst[e];
    float wv = w[e];
    float4 v = table[(size_t)sr * 32 + l];
    float* sp = s + (size_t)dd * F + l * 4;
    unsafeAtomicAdd(sp + 0, v.x * wv);
    unsafeAtomicAdd(sp + 1, v.y * wv);
    unsafeAtomicAdd(sp + 2, v.z * wv);
    unsafeAtomicAdd(sp + 3, v.w * wv);
    if (l == 0) unsafeAtomicAdd(deg + dd, 1.0f);
}

// ---------------------------------------------------------------------------
// Dense layer 1: h = relu(x[:N] @ Ws + (s/deg) @ Wn + b), h written IN PLACE
// over s (rows staged to LDS first; blocks own disjoint rows).
// 16 rows/block, 256 threads, per-thread tile 2 rows x 4 cols.
// ---------------------------------------------------------------------------
#define D1_ROWS 16
__global__ __launch_bounds__(256) void dense1_kernel(
    const float* __restrict__ x, const float* s, const float* __restrict__ deg,
    const float* __restrict__ Ws, const float* __restrict__ Wn,
    const float* __restrict__ b, float* h)
{
    __shared__ float ws[F * F];
    __shared__ float wn[F * F];
    __shared__ float xs[D1_ROWS][F + 2];
    __shared__ float ns[D1_ROWS][F + 2];

    int tid = threadIdx.x;
    for (int i = tid; i < F * F; i += 256) { ws[i] = Ws[i]; wn[i] = Wn[i]; }

    int r0 = blockIdx.x * D1_ROWS;
    for (int i = tid; i < D1_ROWS * F; i += 256) {
        int r = i >> 7, c = i & (F - 1);
        int row = r0 + r;
        xs[r][c] = x[(size_t)row * F + c];
        float rd = 1.0f / fmaxf(deg[row], 1.0f);
        ns[r][c] = s[(size_t)row * F + c] * rd;
    }
    __syncthreads();

    int ct = tid & 31;   // 32 col groups of 4
    int rt = tid >> 5;   // 8 row groups of 2
    int j0 = ct * 4;
    int rr = rt * 2;

    float a0[4] = {0, 0, 0, 0};
    float a1[4] = {0, 0, 0, 0};
    const float4* ws4 = (const float4*)ws;
    const float4* wn4 = (const float4*)wn;

#pragma unroll 4
    for (int k = 0; k < F; ++k) {
        float4 aw = ws4[k * 32 + ct];
        float4 bw = wn4[k * 32 + ct];
        float x0 = xs[rr][k],     n0 = ns[rr][k];
        float x1 = xs[rr + 1][k], n1 = ns[rr + 1][k];
        a0[0] += x0 * aw.x + n0 * bw.x;
        a0[1] += x0 * aw.y + n0 * bw.y;
        a0[2] += x0 * aw.z + n0 * bw.z;
        a0[3] += x0 * aw.w + n0 * bw.w;
        a1[0] += x1 * aw.x + n1 * bw.x;
        a1[1] += x1 * aw.y + n1 * bw.y;
        a1[2] += x1 * aw.z + n1 * bw.z;
        a1[3] += x1 * aw.w + n1 * bw.w;
    }

    float4 bb = *(const float4*)(b + j0);
    float4 o0, o1;
    o0.x = fmaxf(a0[0] + bb.x, 0.0f);
    o0.y = fmaxf(a0[1] + bb.y, 0.0f);
    o0.z = fmaxf(a0[2] + bb.z, 0.0f);
    o0.w = fmaxf(a0[3] + bb.w, 0.0f);
    o1.x = fmaxf(a1[0] + bb.x, 0.0f);
    o1.y = fmaxf(a1[1] + bb.y, 0.0f);
    o1.z = fmaxf(a1[2] + bb.z, 0.0f);
    o1.w = fmaxf(a1[3] + bb.w, 0.0f);
    *(float4*)(h + (size_t)(r0 + rr) * F + j0)     = o0;
    *(float4*)(h + (size_t)(r0 + rr + 1) * F + j0) = o1;
}

// ---------------------------------------------------------------------------
// Dense layer 2 + log_softmax: out = logsoftmax(h[:N2] @ Ws2 + (s2/deg2) @ Wn2 + b2)
// 16 rows/block, 16 threads per row (one per class).
// ---------------------------------------------------------------------------
#define D2_ROWS 16
__global__ __launch_bounds__(256) void dense2_kernel(
    const float* __restrict__ h, const float* __restrict__ s2,
    const float* __restrict__ deg2, const float* __restrict__ Ws,
    const float* __restrict__ Wn, const float* __restrict__ b,
    float* __restrict__ out)
{
    __shared__ float ws[F * NCLS];
    __shared__ float wn[F * NCLS];
    __shared__ float hs[D2_ROWS][F + 1];
    __shared__ float ns[D2_ROWS][F + 1];

    int tid = threadIdx.x;
    for (int i = tid; i < F * NCLS; i += 256) { ws[i] = Ws[i]; wn[i] = Wn[i]; }

    int r0 = blockIdx.x * D2_ROWS;
    for (int i = tid; i < D2_ROWS * F; i += 256) {
        int r = i >> 7, c = i & (F - 1);
        int row = r0 + r;
        hs[r][c] = h[(size_t)row * F + c];
        float rd = 1.0f / fmaxf(deg2[row], 1.0f);
        ns[r][c] = s2[(size_t)row * F + c] * rd;
    }
    __syncthreads();

    int r = tid >> 4;   // 16 rows
    int j = tid & 15;   // 16 classes
    float acc = b[j];
#pragma unroll 8
    for (int k = 0; k < F; ++k) {
        acc += hs[r][k] * ws[k * NCLS + j] + ns[r][k] * wn[k * NCLS + j];
    }

    // log_softmax across the 16 lanes of this row
    float m = acc;
    for (int o = 8; o >= 1; o >>= 1) m = fmaxf(m, __shfl_xor(m, o, 16));
    float ex = expf(acc - m);
    float ssum = ex;
    for (int o = 8; o >= 1; o >>= 1) ssum += __shfl_xor(ssum, o, 16);
    out[(size_t)(r0 + r) * NCLS + j] = acc - m - logf(ssum);
}

// ---------------------------------------------------------------------------
extern "C" void kernel_launch(void* const* d_in, const int* in_sizes, int n_in,
                              void* d_out, int out_size, void* d_ws, size_t ws_size,
                              hipStream_t stream)
{
    const float* x    = (const float*)d_in[0];
    const int*   src1 = (const int*)d_in[1];
    const int*   dst1 = (const int*)d_in[2];
    const float* w1   = (const float*)d_in[3];
    const int*   src2 = (const int*)d_in[4];
    const int*   dst2 = (const int*)d_in[5];
    const float* w2   = (const float*)d_in[6];
    const float* Ws1  = (const float*)d_in[7];
    const float* Wn1  = (const float*)d_in[8];
    const float* b1   = (const float*)d_in[9];
    const float* Ws2  = (const float*)d_in[10];
    const float* Wn2  = (const float*)d_in[11];
    const float* b2   = (const float*)d_in[12];
    float* out = (float*)d_out;

    // workspace layout (floats):
    //   s1 (aliased as h after dense1): NDST1*F
    //   deg1: NDST1
    //   s2:   NDST2*F
    //   deg2: NDST2
    float* wsf  = (float*)d_ws;
    float* s1   = wsf;                          // also h (in-place)
    float* deg1 = s1 + (size_t)NDST1 * F;
    float* s2   = deg1 + NDST1;
    float* deg2 = s2 + (size_t)NDST2 * F;
    float* h    = s1;

    size_t zero_floats = (size_t)NDST1 * F + NDST1 + (size_t)NDST2 * F + NDST2;
    hipMemsetAsync(d_ws, 0, zero_floats * sizeof(float), stream);

    edge_kernel<<<(NE1 * 32) / 256, 256, 0, stream>>>(
        (const float4*)x, src1, dst1, w1, s1, deg1, NE1);

    dense1_kernel<<<NDST1 / D1_ROWS, 256, 0, stream>>>(
        x, s1, deg1, Ws1, Wn1, b1, h);

    edge_kernel<<<(NE2 * 32) / 256, 256, 0, stream>>>(
        (const float4*)h, src2, dst2, w2, s2, deg2, NE2);

    dense2_kernel<<<NDST2 / D2_ROWS, 256, 0, stream>>>(
        h, s2, deg2, Ws2, Wn2, b2, out);
}

// Round 2
// 1253.372 us; speedup vs baseline: 4.3832x; 4.3832x over previous
//
#include <hip/hip_runtime.h>

#define NSRC1 500000
#define NDST1 100000
#define NDST2 20000
#define NE1   2000000
#define NE2   1000000
#define F     128
#define NCLS  16

// ---------------------------------------------------------------------------
// Workspace layout (bytes):
//   [0,        400000)   cnt1   (NDST1 ints)  -- histogram, destroyed by fill
//   [400000,   480000)   cnt2   (NDST2 ints)  -- deg2
//   [480000,  1760000)   s2proj (NDST2*16 f)  -- projected layer-2 accumulator
//   [1760000, 2160004)   starts1 (NDST1+1 ints)
//   [2160016, 10160016)  eidx   (NE1 ints)    -- CSR edge ids
//   [10160016,16560016)  g      (NDST1*16 f)  -- h @ Wn2
//   [16560016,26800016)  hsmall (NDST2*F f)   -- h[:NDST2]
// total ~26.8 MB (proven safe: round 1 used 51.7 MB)
// ---------------------------------------------------------------------------

__global__ __launch_bounds__(256) void hist_kernel(
    const int* __restrict__ dst1, const int* __restrict__ dst2,
    int* __restrict__ cnt1, int* __restrict__ cnt2)
{
    int t = blockIdx.x * 256 + threadIdx.x;
    if (t < NE1) atomicAdd(&cnt1[dst1[t]], 1);
    else if (t < NE1 + NE2) atomicAdd(&cnt2[dst2[t - NE1]], 1);
}

// single-block exclusive scan over n counts -> starts[0..n]
__global__ __launch_bounds__(1024) void scan_kernel(
    const int* __restrict__ cnt, int* __restrict__ starts, int n)
{
    __shared__ int buf[2][1024];
    __shared__ int carry_s;
    int tid = threadIdx.x;
    if (tid == 0) carry_s = 0;
    __syncthreads();
    for (int base = 0; base < n; base += 1024) {
        int v = (base + tid < n) ? cnt[base + tid] : 0;
        int cur = 0;
        buf[0][tid] = v;
        __syncthreads();
        for (int off = 1; off < 1024; off <<= 1) {
            int t = buf[cur][tid];
            if (tid >= off) t += buf[cur][tid - off];
            buf[cur ^ 1][tid] = t;
            cur ^= 1;
            __syncthreads();
        }
        int inc = buf[cur][tid];
        int carry = carry_s;
        __syncthreads();
        if (base + tid < n) starts[base + tid] = carry + inc - v;
        if (tid == 1023) carry_s = carry + inc;
        __syncthreads();
    }
    if (tid == 0) starts[n] = carry_s;
}

__global__ __launch_bounds__(256) void fill_kernel(
    const int* __restrict__ dst1, int* __restrict__ cnt1,
    const int* __restrict__ starts, int* __restrict__ eidx)
{
    int t = blockIdx.x * 256 + threadIdx.x;
    if (t >= NE1) return;
    int d = dst1[t];
    int k = atomicSub(&cnt1[d], 1) - 1;
    eidx[starts[d] + k] = t;
}

// ---------------------------------------------------------------------------
// Fused layer 1: per block = 16 dst rows.
//  phase 1: gather neigh rows (32 lanes/row, float4/lane, CSR)
//  phase 2: h = relu(x@Ws + neigh@Wn + b)   (128 threads, 4 rows x 4 cols ea)
//  phase 3: g = h @ Wn2 (128->16 projection for layer 2)
// ---------------------------------------------------------------------------
__global__ __launch_bounds__(512) void fused1_kernel(
    const float4* __restrict__ x4, const int* __restrict__ src,
    const float* __restrict__ w, const int* __restrict__ eidx,
    const int* __restrict__ starts,
    const float* __restrict__ Ws, const float* __restrict__ Wn,
    const float* __restrict__ b, const float* __restrict__ Wn2,
    float* __restrict__ hsmall, float* __restrict__ g)
{
    __shared__ float ws[F * F];     // 64 KB
    __shared__ float wn[F * F];     // 64 KB
    __shared__ float xs[16][F];     // 8 KB
    __shared__ float ns[16][F];     // 8 KB
    __shared__ float hs[16][F];     // 8 KB   total 152 KB

    int tid = threadIdx.x;
    {   // stage W1 self+neigh
        const float4* Ws4 = (const float4*)Ws;
        const float4* Wn4 = (const float4*)Wn;
        float4* wsv = (float4*)ws;
        float4* wnv = (float4*)wn;
        for (int i = tid; i < F * F / 4; i += 512) { wsv[i] = Ws4[i]; wnv[i] = Wn4[i]; }
    }

    int grp = tid >> 5, l = tid & 31;
    int row = blockIdx.x * 16 + grp;
    int st = starts[row], en = starts[row + 1];
    float4 acc = make_float4(0.f, 0.f, 0.f, 0.f);
    int i = st;
    for (; i + 4 <= en; i += 4) {
        int e0 = eidx[i], e1 = eidx[i + 1], e2 = eidx[i + 2], e3 = eidx[i + 3];
        int s0 = src[e0], s1 = src[e1], s2 = src[e2], s3 = src[e3];
        float w0 = w[e0], w1 = w[e1], w2 = w[e2], w3 = w[e3];
        float4 v0 = x4[(size_t)s0 * 32 + l];
        float4 v1 = x4[(size_t)s1 * 32 + l];
        float4 v2 = x4[(size_t)s2 * 32 + l];
        float4 v3 = x4[(size_t)s3 * 32 + l];
        acc.x += v0.x * w0 + v1.x * w1 + v2.x * w2 + v3.x * w3;
        acc.y += v0.y * w0 + v1.y * w1 + v2.y * w2 + v3.y * w3;
        acc.z += v0.z * w0 + v1.z * w1 + v2.z * w2 + v3.z * w3;
        acc.w += v0.w * w0 + v1.w * w1 + v2.w * w2 + v3.w * w3;
    }
    for (; i < en; ++i) {
        int e0 = eidx[i];
        int s0 = src[e0];
        float w0 = w[e0];
        float4 v0 = x4[(size_t)s0 * 32 + l];
        acc.x += v0.x * w0; acc.y += v0.y * w0; acc.z += v0.z * w0; acc.w += v0.w * w0;
    }
    float invd = 1.0f / fmaxf((float)(en - st), 1.0f);
    acc.x *= invd; acc.y *= invd; acc.z *= invd; acc.w *= invd;
    float4 xr = x4[(size_t)row * 32 + l];
    *(float4*)&xs[grp][l * 4] = xr;
    *(float4*)&ns[grp][l * 4] = acc;
    __syncthreads();

    // phase 2: matvec, 128 active threads: ct=col-group(4 cols), rt=row-group(4 rows)
    if (tid < 128) {
        int ct = tid & 31, rt = tid >> 5;
        float a[4][4] = {{0.f}};
        const float4* wsv = (const float4*)ws;
        const float4* wnv = (const float4*)wn;
#pragma unroll 4
        for (int k = 0; k < F; ++k) {
            float4 aw = wsv[k * 32 + ct];
            float4 bw = wnv[k * 32 + ct];
#pragma unroll
            for (int r = 0; r < 4; ++r) {
                float xv = xs[rt * 4 + r][k];
                float nv = ns[rt * 4 + r][k];
                a[r][0] += xv * aw.x + nv * bw.x;
                a[r][1] += xv * aw.y + nv * bw.y;
                a[r][2] += xv * aw.z + nv * bw.z;
                a[r][3] += xv * aw.w + nv * bw.w;
            }
        }
        float4 bb = ((const float4*)b)[ct];
#pragma unroll
        for (int r = 0; r < 4; ++r) {
            float4 ov;
            ov.x = fmaxf(a[r][0] + bb.x, 0.f);
            ov.y = fmaxf(a[r][1] + bb.y, 0.f);
            ov.z = fmaxf(a[r][2] + bb.z, 0.f);
            ov.w = fmaxf(a[r][3] + bb.w, 0.f);
            int rr = rt * 4 + r;
            *(float4*)&hs[rr][ct * 4] = ov;
            int grow = blockIdx.x * 16 + rr;
            if (grow < NDST2) ((float4*)hsmall)[(size_t)grow * 32 + ct] = ov;
        }
    }
    __syncthreads();

    // phase 3: g[row] = h[row] @ Wn2, lanes split c-range in halves
    {
        int half = l >> 4, j = l & 15;
        float gv = 0.f;
        int c0 = half * 64;
#pragma unroll 8
        for (int c = c0; c < c0 + 64; ++c)
            gv += hs[grp][c] * Wn2[c * NCLS + j];
        gv += __shfl_xor(gv, 16);
        if (half == 0) g[(size_t)row * NCLS + j] = gv;
    }
}

// ---------------------------------------------------------------------------
// Layer-2 scatter on projected features: s2proj[dst] += g[src]*w  (16 floats)
// ---------------------------------------------------------------------------
__global__ __launch_bounds__(256) void scatter2_kernel(
    const float4* __restrict__ g4, const int* __restrict__ src,
    const int* __restrict__ dst, const float* __restrict__ w,
    float* __restrict__ s2p)
{
    int t = blockIdx.x * 256 + threadIdx.x;
    int e = t >> 2, l = t & 3;
    if (e >= NE2) return;
    float wv = w[e];
    float4 v = g4[(size_t)src[e] * 4 + l];
    float* p = s2p + (size_t)dst[e] * 16 + l * 4;
    unsafeAtomicAdd(p + 0, v.x * wv);
    unsafeAtomicAdd(p + 1, v.y * wv);
    unsafeAtomicAdd(p + 2, v.z * wv);
    unsafeAtomicAdd(p + 3, v.w * wv);
}

// ---------------------------------------------------------------------------
// Dense layer 2 + log_softmax: out = lsm(h2@Ws2 + s2proj/deg2 + b2)
// ---------------------------------------------------------------------------
__global__ __launch_bounds__(256) void dense2_kernel(
    const float* __restrict__ hsmall, const float* __restrict__ s2p,
    const int* __restrict__ cnt2, const float* __restrict__ Ws2,
    const float* __restrict__ b2, float* __restrict__ out)
{
    __shared__ float ws[F * NCLS];
    __shared__ float hsh[16][F + 1];
    int tid = threadIdx.x;
    for (int i = tid; i < F * NCLS; i += 256) ws[i] = Ws2[i];
    int r0 = blockIdx.x * 16;
    for (int i = tid; i < 16 * F; i += 256) {
        int r = i >> 7, c = i & 127;
        hsh[r][c] = hsmall[(size_t)(r0 + r) * F + c];
    }
    __syncthreads();
    int r = tid >> 4, j = tid & 15;
    int row = r0 + r;
    float invd = 1.0f / fmaxf((float)cnt2[row], 1.0f);
    float acc = b2[j] + s2p[(size_t)row * 16 + j] * invd;
#pragma unroll 8
    for (int k = 0; k < F; ++k)
        acc += hsh[r][k] * ws[k * NCLS + j];
    float m = acc;
    for (int o = 8; o >= 1; o >>= 1) m = fmaxf(m, __shfl_xor(m, o, 16));
    float s = expf(acc - m);
    for (int o = 8; o >= 1; o >>= 1) s += __shfl_xor(s, o, 16);
    out[(size_t)row * NCLS + j] = acc - m - logf(s);
}

// ---------------------------------------------------------------------------
extern "C" void kernel_launch(void* const* d_in, const int* in_sizes, int n_in,
                              void* d_out, int out_size, void* d_ws, size_t ws_size,
                              hipStream_t stream)
{
    const float* x    = (const float*)d_in[0];
    const int*   src1 = (const int*)d_in[1];
    const int*   dst1 = (const int*)d_in[2];
    const float* w1   = (const float*)d_in[3];
    const int*   src2 = (const int*)d_in[4];
    const int*   dst2 = (const int*)d_in[5];
    const float* w2   = (const float*)d_in[6];
    const float* Ws1  = (const float*)d_in[7];
    const float* Wn1  = (const float*)d_in[8];
    const float* b1   = (const float*)d_in[9];
    const float* Ws2  = (const float*)d_in[10];
    const float* Wn2  = (const float*)d_in[11];
    const float* b2   = (const float*)d_in[12];
    float* out = (float*)d_out;

    char* wsb = (char*)d_ws;
    int*   cnt1    = (int*)(wsb + 0);
    int*   cnt2    = (int*)(wsb + 400000);
    float* s2proj  = (float*)(wsb + 480000);
    int*   starts1 = (int*)(wsb + 1760000);
    int*   eidx    = (int*)(wsb + 2160016);
    float* g       = (float*)(wsb + 10160016);
    float* hsmall  = (float*)(wsb + 16560016);

    // zero cnt1 + cnt2 + s2proj (contiguous)
    hipMemsetAsync(d_ws, 0, 1760000, stream);

    hist_kernel<<<(NE1 + NE2 + 255) / 256, 256, 0, stream>>>(dst1, dst2, cnt1, cnt2);
    scan_kernel<<<1, 1024, 0, stream>>>(cnt1, starts1, NDST1);
    fill_kernel<<<(NE1 + 255) / 256, 256, 0, stream>>>(dst1, cnt1, starts1, eidx);

    fused1_kernel<<<NDST1 / 16, 512, 0, stream>>>(
        (const float4*)x, src1, w1, eidx, starts1, Ws1, Wn1, b1, Wn2, hsmall, g);

    scatter2_kernel<<<(NE2 * 4 + 255) / 256, 256, 0, stream>>>(
        (const float4*)g, src2, dst2, w2, s2proj);

    dense2_kernel<<<NDST2 / 16, 256, 0, stream>>>(
        hsmall, s2proj, cnt2, Ws2, b2, out);
}

// Round 3
// 918.961 us; speedup vs baseline: 5.9782x; 1.3639x over previous
//
#include <hip/hip_runtime.h>

#define NSRC1 500000
#define NDST1 100000
#define NDST2 20000
#define NE1   2000000
#define NE2   1000000
#define F     128
#define NCLS  16
#define NB1   ((NDST1 + 1023) / 1024)   // 98 scan blocks

// ---------------------------------------------------------------------------
// Workspace layout (bytes), total ~34.8 MB (round-1 proved >= 62 MB exists):
//   [0,        400000)   cnt1   (NDST1 ints)
//   [400000,   480000)   cnt2   (NDST2 ints) = deg2
//   [480000,  1760000)   s2proj (NDST2*16 f)
//   [1760000, 2160004)   starts (NDST1+1 ints)
//   [2160128, 2160640)   btot   (scan partials)
//   [2160640, 2161152)   boff
//   [2161152,18161152)   csr_sw ({src,w} int2 per edge, dst-bucketed)
//   [18161152,24561152)  g      (NDST1*16 f)
//   [24561152,34801152)  hsmall (NDST2*F f)
// ---------------------------------------------------------------------------

__global__ __launch_bounds__(256) void hist_kernel(
    const int* __restrict__ dst1, const int* __restrict__ dst2,
    int* __restrict__ cnt1, int* __restrict__ cnt2)
{
    int t = blockIdx.x * 256 + threadIdx.x;
    if (t < NE1) atomicAdd(&cnt1[dst1[t]], 1);
    else if (t < NE1 + NE2) atomicAdd(&cnt2[dst2[t - NE1]], 1);
}

// pass 1: per-block exclusive scan of 1024-chunk, emit block totals
__global__ __launch_bounds__(1024) void scan1_kernel(
    const int* __restrict__ cnt, int* __restrict__ starts, int* __restrict__ btot)
{
    __shared__ int buf[2][1024];
    int tid = threadIdx.x;
    int i = blockIdx.x * 1024 + tid;
    int v = (i < NDST1) ? cnt[i] : 0;
    buf[0][tid] = v;
    __syncthreads();
    int cur = 0;
    for (int off = 1; off < 1024; off <<= 1) {
        int t = buf[cur][tid];
        if (tid >= off) t += buf[cur][tid - off];
        buf[cur ^ 1][tid] = t;
        cur ^= 1;
        __syncthreads();
    }
    int inc = buf[cur][tid];
    if (i < NDST1) starts[i] = inc - v;
    if (tid == 1023) btot[blockIdx.x] = inc;
}

// pass 2: scan the 98 block totals (one 128-thread block)
__global__ __launch_bounds__(128) void scan2_kernel(
    const int* __restrict__ btot, int* __restrict__ boff, int* __restrict__ starts)
{
    __shared__ int buf[2][128];
    int tid = threadIdx.x;
    int v = (tid < NB1) ? btot[tid] : 0;
    buf[0][tid] = v;
    __syncthreads();
    int cur = 0;
    for (int off = 1; off < 128; off <<= 1) {
        int t = buf[cur][tid];
        if (tid >= off) t += buf[cur][tid - off];
        buf[cur ^ 1][tid] = t;
        cur ^= 1;
        __syncthreads();
    }
    int inc = buf[cur][tid];
    if (tid < NB1) boff[tid] = inc - v;
    if (tid == NB1 - 1) starts[NDST1] = inc;
}

// pass 3: add block offsets back
__global__ __launch_bounds__(1024) void scan3_kernel(
    int* __restrict__ starts, const int* __restrict__ boff)
{
    int i = blockIdx.x * 1024 + threadIdx.x;
    if (i < NDST1) starts[i] += boff[blockIdx.x];
}

// bucket-fill: csr_sw[pos] = {src, w} packed 8B
__global__ __launch_bounds__(256) void fill_kernel(
    const int* __restrict__ dst1, const int* __restrict__ src1,
    const float* __restrict__ w1, int* __restrict__ cnt1,
    const int* __restrict__ starts, int2* __restrict__ csr)
{
    int t = blockIdx.x * 256 + threadIdx.x;
    if (t >= NE1) return;
    int d = dst1[t];
    int k = atomicSub(&cnt1[d], 1) - 1;
    csr[starts[d] + k] = make_int2(src1[t], __float_as_int(w1[t]));
}

// ---------------------------------------------------------------------------
// Fused layer 1: 8 dst rows / 256-thread block, small LDS -> high occupancy.
//  phase 1: CSR gather mean (32 lanes/row, float4/lane)
//  phase 2: h = relu(x@Ws + ns@Wn + b)  (weights read from L2, 1 row x 4 col/thr)
//  phase 3: g = h @ Wn2 ; h[:NDST2] -> hsmall
// ---------------------------------------------------------------------------
#define FP 132   // padded row to break 8-way LDS bank conflicts
__global__ __launch_bounds__(256, 6) void fused1_kernel(
    const float4* __restrict__ x4, const int2* __restrict__ csr,
    const int* __restrict__ starts,
    const float* __restrict__ Ws, const float* __restrict__ Wn,
    const float* __restrict__ b, const float* __restrict__ Wn2,
    float* __restrict__ hsmall, float* __restrict__ g)
{
    __shared__ float xs[8][FP];
    __shared__ float ns[8][FP];
    __shared__ float hs[8][FP];

    int tid = threadIdx.x;
    int grp = tid >> 5, l = tid & 31;
    int row = blockIdx.x * 8 + grp;

    int st = starts[row], en = starts[row + 1];
    float4 acc = make_float4(0.f, 0.f, 0.f, 0.f);
    int i = st;
    for (; i + 4 <= en; i += 4) {
        int2 e0 = csr[i], e1 = csr[i + 1], e2 = csr[i + 2], e3 = csr[i + 3];
        float w0 = __int_as_float(e0.y), w1 = __int_as_float(e1.y);
        float w2 = __int_as_float(e2.y), w3 = __int_as_float(e3.y);
        float4 v0 = x4[(size_t)e0.x * 32 + l];
        float4 v1 = x4[(size_t)e1.x * 32 + l];
        float4 v2 = x4[(size_t)e2.x * 32 + l];
        float4 v3 = x4[(size_t)e3.x * 32 + l];
        acc.x += v0.x * w0 + v1.x * w1 + v2.x * w2 + v3.x * w3;
        acc.y += v0.y * w0 + v1.y * w1 + v2.y * w2 + v3.y * w3;
        acc.z += v0.z * w0 + v1.z * w1 + v2.z * w2 + v3.z * w3;
        acc.w += v0.w * w0 + v1.w * w1 + v2.w * w2 + v3.w * w3;
    }
    for (; i < en; ++i) {
        int2 e0 = csr[i];
        float w0 = __int_as_float(e0.y);
        float4 v0 = x4[(size_t)e0.x * 32 + l];
        acc.x += v0.x * w0; acc.y += v0.y * w0; acc.z += v0.z * w0; acc.w += v0.w * w0;
    }
    float invd = 1.0f / fmaxf((float)(en - st), 1.0f);
    acc.x *= invd; acc.y *= invd; acc.z *= invd; acc.w *= invd;
    float4 xr = x4[(size_t)row * 32 + l];
    *(float4*)&xs[grp][l * 4] = xr;
    *(float4*)&ns[grp][l * 4] = acc;
    __syncthreads();

    // phase 2: ct = col group (4 cols), rt = row (8 rows). Weights from L2.
    {
        int ct = tid & 31, rt = tid >> 5;
        float a0 = 0.f, a1 = 0.f, a2 = 0.f, a3 = 0.f;
        const float4* wsv = (const float4*)Ws;
        const float4* wnv = (const float4*)Wn;
#pragma unroll 4
        for (int k = 0; k < F; ++k) {
            float4 aw = wsv[k * 32 + ct];
            float4 bw = wnv[k * 32 + ct];
            float xv = xs[rt][k];
            float nv = ns[rt][k];
            a0 += xv * aw.x + nv * bw.x;
            a1 += xv * aw.y + nv * bw.y;
            a2 += xv * aw.z + nv * bw.z;
            a3 += xv * aw.w + nv * bw.w;
        }
        float4 bb = ((const float4*)b)[ct];
        float4 ov;
        ov.x = fmaxf(a0 + bb.x, 0.f);
        ov.y = fmaxf(a1 + bb.y, 0.f);
        ov.z = fmaxf(a2 + bb.z, 0.f);
        ov.w = fmaxf(a3 + bb.w, 0.f);
        int rrow = blockIdx.x * 8 + rt;
        *(float4*)&hs[rt][ct * 4] = ov;
        if (rrow < NDST2) ((float4*)hsmall)[(size_t)rrow * 32 + ct] = ov;
    }
    __syncthreads();

    // phase 3: g[row] = h[row] @ Wn2  (128 threads: r in [0,8), j in [0,16))
    if (tid < 128) {
        int r = tid >> 4, j = tid & 15;
        float gv = 0.f;
#pragma unroll 8
        for (int c = 0; c < F; ++c)
            gv += hs[r][c] * Wn2[c * NCLS + j];
        g[(size_t)(blockIdx.x * 8 + r) * NCLS + j] = gv;
    }
}

// ---------------------------------------------------------------------------
// Layer-2 scatter on projected features: s2proj[dst] += g[src]*w (16 floats)
// ---------------------------------------------------------------------------
__global__ __launch_bounds__(256) void scatter2_kernel(
    const float4* __restrict__ g4, const int* __restrict__ src,
    const int* __restrict__ dst, const float* __restrict__ w,
    float* __restrict__ s2p)
{
    int t = blockIdx.x * 256 + threadIdx.x;
    int e = t >> 2, l = t & 3;
    if (e >= NE2) return;
    float wv = w[e];
    float4 v = g4[(size_t)src[e] * 4 + l];
    float* p = s2p + (size_t)dst[e] * 16 + l * 4;
    unsafeAtomicAdd(p + 0, v.x * wv);
    unsafeAtomicAdd(p + 1, v.y * wv);
    unsafeAtomicAdd(p + 2, v.z * wv);
    unsafeAtomicAdd(p + 3, v.w * wv);
}

// ---------------------------------------------------------------------------
// Dense layer 2 + log_softmax
// ---------------------------------------------------------------------------
__global__ __launch_bounds__(256) void dense2_kernel(
    const float* __restrict__ hsmall, const float* __restrict__ s2p,
    const int* __restrict__ cnt2, const float* __restrict__ Ws2,
    const float* __restrict__ b2, float* __restrict__ out)
{
    __shared__ float ws[F * NCLS];
    __shared__ float hsh[16][F + 1];
    int tid = threadIdx.x;
    for (int i = tid; i < F * NCLS; i += 256) ws[i] = Ws2[i];
    int r0 = blockIdx.x * 16;
    for (int i = tid; i < 16 * F; i += 256) {
        int r = i >> 7, c = i & 127;
        hsh[r][c] = hsmall[(size_t)(r0 + r) * F + c];
    }
    __syncthreads();
    int r = tid >> 4, j = tid & 15;
    int row = r0 + r;
    float invd = 1.0f / fmaxf((float)cnt2[row], 1.0f);
    float acc = b2[j] + s2p[(size_t)row * 16 + j] * invd;
#pragma unroll 8
    for (int k = 0; k < F; ++k)
        acc += hsh[r][k] * ws[k * NCLS + j];
    float m = acc;
    for (int o = 8; o >= 1; o >>= 1) m = fmaxf(m, __shfl_xor(m, o, 16));
    float s = expf(acc - m);
    for (int o = 8; o >= 1; o >>= 1) s += __shfl_xor(s, o, 16);
    out[(size_t)row * NCLS + j] = acc - m - logf(s);
}

// ---------------------------------------------------------------------------
extern "C" void kernel_launch(void* const* d_in, const int* in_sizes, int n_in,
                              void* d_out, int out_size, void* d_ws, size_t ws_size,
                              hipStream_t stream)
{
    const float* x    = (const float*)d_in[0];
    const int*   src1 = (const int*)d_in[1];
    const int*   dst1 = (const int*)d_in[2];
    const float* w1   = (const float*)d_in[3];
    const int*   src2 = (const int*)d_in[4];
    const int*   dst2 = (const int*)d_in[5];
    const float* w2   = (const float*)d_in[6];
    const float* Ws1  = (const float*)d_in[7];
    const float* Wn1  = (const float*)d_in[8];
    const float* b1   = (const float*)d_in[9];
    const float* Ws2  = (const float*)d_in[10];
    const float* Wn2  = (const float*)d_in[11];
    const float* b2   = (const float*)d_in[12];
    float* out = (float*)d_out;

    char* wsb = (char*)d_ws;
    int*   cnt1   = (int*)(wsb + 0);
    int*   cnt2   = (int*)(wsb + 400000);
    float* s2proj = (float*)(wsb + 480000);
    int*   starts = (int*)(wsb + 1760000);
    int*   btot   = (int*)(wsb + 2160128);
    int*   boff   = (int*)(wsb + 2160640);
    int2*  csr    = (int2*)(wsb + 2161152);
    float* g      = (float*)(wsb + 18161152);
    float* hsmall = (float*)(wsb + 24561152);

    // zero cnt1 + cnt2 + s2proj (contiguous front region)
    hipMemsetAsync(d_ws, 0, 1760000, stream);

    hist_kernel<<<(NE1 + NE2 + 255) / 256, 256, 0, stream>>>(dst1, dst2, cnt1, cnt2);
    scan1_kernel<<<NB1, 1024, 0, stream>>>(cnt1, starts, btot);
    scan2_kernel<<<1, 128, 0, stream>>>(btot, boff, starts);
    scan3_kernel<<<NB1, 1024, 0, stream>>>(starts, boff);
    fill_kernel<<<(NE1 + 255) / 256, 256, 0, stream>>>(dst1, src1, w1, cnt1, starts, csr);

    fused1_kernel<<<NDST1 / 8, 256, 0, stream>>>(
        (const float4*)x, csr, starts, Ws1, Wn1, b1, Wn2, hsmall, g);

    scatter2_kernel<<<(NE2 * 4 + 255) / 256, 256, 0, stream>>>(
        (const float4*)g, src2, dst2, w2, s2proj);

    dense2_kernel<<<NDST2 / 16, 256, 0, stream>>>(
        hsmall, s2proj, cnt2, Ws2, b2, out);
}